// Round 12
// baseline (673.535 us; speedup 1.0000x reference)
//
#include <hip/hip_runtime.h>
#include <math.h>

// Problem geometry (fixed by setup_inputs)
#define BB    256   // batch
#define DIN   2048  // layer-0 input dim
#define HH    512   // hidden dim
#define NSL   16    // i-slice split
#define GRIDB 2048  // (HH/4) * NSL blocks = 8/CU (exactly resident capacity)

#define NEG_HALF_LOG2E (-0.72134752044448170368f)
#define LOG2E           1.44269504088896340736f
#define LN2             0.69314718055994530942f

typedef float v2f __attribute__((ext_vector_type(2)));

__device__ __forceinline__ float fexp2(float x) { return __builtin_amdgcn_exp2f(x); }
__device__ __forceinline__ float silu_f(float y)
{
    return y * __builtin_amdgcn_rcpf(1.f + fexp2(-y * LOG2E));
}

// ---------------------------------------------------------------------------
// tz: transpose x [BB][DIN] -> x4 [DIN/4][BB], zero acc, zero counters.
// ---------------------------------------------------------------------------
__global__ __launch_bounds__(256) void tz_k(
    const float* __restrict__ in, float4* __restrict__ out4,
    float* __restrict__ acc, int* __restrict__ cnt)
{
    __shared__ float tile[32][33];
    int bid = blockIdx.x, t = threadIdx.x;
    acc[bid * 256 + t] = 0.0f;                 // 512*256 == HH*BB exactly
    if (bid == 0 && t < 3) cnt[t] = 0;
    int ct = bid & 63, rt = bid >> 6;          // 64 c-tiles x 8 r-tiles
    int c0 = ct * 32, r0 = rt * 32;
    int tx = t & 31, ty = t >> 5;              // (32, 8)
#pragma unroll
    for (int k = 0; k < 4; k++)
        tile[ty + 8*k][tx] = in[(size_t)(r0 + ty + 8*k) * DIN + c0 + tx];
    __syncthreads();
    float4 v = make_float4(tile[tx][4*ty + 0], tile[tx][4*ty + 1],
                           tile[tx][4*ty + 2], tile[tx][4*ty + 3]);
    out4[(size_t)(c0/4 + ty) * BB + (r0 + tx)] = v;
}

// ---------------------------------------------------------------------------
// wavelet kernel + fused finish (completion-counter tail).
// Wavelet part identical to R9 (o=4 per block, LDS param self-pack).
// After atomics: fence, count; the last BB linear block-ids wait until all
// GRIDB blocks counted, then each finishes one batch b (SiLU+LN(+cls)).
// Deadlock-free: spinners <= 256 blocks, worker blocks (1792) always fit in
// the remaining resident slots and never wait on spinners.
// ---------------------------------------------------------------------------
#define WAV_RR(PB, OFF, XSC) {                                    \
    float4 R = *(const float4*)((PB) + (OFF));                    \
    float4 T = *(const float4*)((PB) + (OFF) + 4);                \
    float4 W = *(const float4*)((PB) + (OFF) + 8);                \
    v2f xx  = {(XSC), (XSC)};                                     \
    v2f R01 = {R.x, R.y}, R23 = {R.z, R.w};                       \
    v2f T01 = {T.x, T.y}, T23 = {T.z, T.w};                       \
    v2f W01 = {W.x, W.y}, W23 = {W.z, W.w};                       \
    v2f d01 = __builtin_elementwise_fma(xx, R01, -T01);           \
    v2f d23 = __builtin_elementwise_fma(xx, R23, -T23);           \
    v2f u01 = d01 * d01,  u23 = d23 * d23;                        \
    v2f g01 = u01 * k2,   g23 = u23 * k2;                         \
    v2f e01, e23;                                                 \
    e01.x = fexp2(g01.x); e01.y = fexp2(g01.y);                   \
    e23.x = fexp2(g23.x); e23.y = fexp2(g23.y);                   \
    v2f p01 = __builtin_elementwise_fma(-W01, u01, W01);          \
    v2f p23 = __builtin_elementwise_fma(-W23, u23, W23);          \
    a01 = __builtin_elementwise_fma(p01, e01, a01);               \
    a23 = __builtin_elementwise_fma(p23, e23, a23); }

template<int D, int CLS>
__global__ __launch_bounds__(256, 8) void wavf_k(
    const float4* __restrict__ x4,
    const float*  __restrict__ ss,
    const float*  __restrict__ tt,
    const float*  __restrict__ ww,
    float* __restrict__ acc, int* __restrict__ cnt,
    const float* __restrict__ g, const float* __restrict__ be,
    float4* __restrict__ fout4,
    const float* __restrict__ cw, const float* __restrict__ cb,
    float* __restrict__ out)
{
    constexpr int G     = (D / 4) / NSL;   // 32 (L0) or 8 (L1/2)
    constexpr int SLICE = G * 4;           // 128 or 32
    constexpr int LSH   = (SLICE == 128) ? 7 : 5;

    __shared__ float P[G * 48];
    __shared__ float ls[4];

    const int q  = blockIdx.x;             // o-quad
    const int sl = blockIdx.y;             // i-slice
    const int t  = threadIdx.x;

    // ---- self-pack param slice into LDS ----
    for (int e = t; e < 4 * SLICE; e += 256) {
        int oo = e >> LSH;                 // 0..3
        int ii = e & (SLICE - 1);
        size_t idx = (size_t)(q * 4 + oo) * D + (size_t)sl * SLICE + ii;
        float v  = ss[idx];
        float e2 = fexp2(-fabsf(v) * LOG2E);
        float sp = fmaxf(v, 0.0f) + LN2 * __builtin_amdgcn_logf(1.0f + e2);
        float rv = __builtin_amdgcn_rcpf(0.001f + sp + 1e-8f);
        int gg = ii >> 2, rr = ii & 3;
        P[gg * 48 + rr * 12 + 0 + oo] = rv;
        P[gg * 48 + rr * 12 + 4 + oo] = tt[idx] * rv;
        P[gg * 48 + rr * 12 + 8 + oo] = ww[idx];
    }
    __syncthreads();

    // ---- wavelet loop ----
    const float4* xp = x4 + (size_t)sl * G * BB + t;
    v2f a01 = {0.f, 0.f}, a23 = {0.f, 0.f};
    const v2f k2 = {NEG_HALF_LOG2E, NEG_HALF_LOG2E};

#pragma unroll 2
    for (int gi = 0; gi < G; ++gi) {
        const float* pb = &P[gi * 48];
        float4 xv = xp[(size_t)gi * BB];
        WAV_RR(pb,  0, xv.x)
        WAV_RR(pb, 12, xv.y)
        WAV_RR(pb, 24, xv.z)
        WAV_RR(pb, 36, xv.w)
    }

    float* dst = acc + (size_t)(4 * q) * BB + t;
    unsafeAtomicAdd(dst,        a01.x);
    unsafeAtomicAdd(dst + BB,   a01.y);
    unsafeAtomicAdd(dst + 2*BB, a23.x);
    unsafeAtomicAdd(dst + 3*BB, a23.y);

    // ---- completion count (block-level release) ----
    __threadfence();
    __syncthreads();
    if (t == 0) atomicAdd(cnt, 1);

    // ---- fused finish: last BB linear block-ids each handle one batch b ----
    const int lbid = sl * (HH / 4) + q;
    if (lbid >= GRIDB - BB) {
        if (t == 0) {
            while (__hip_atomic_load(cnt, __ATOMIC_ACQUIRE,
                                     __HIP_MEMORY_SCOPE_AGENT) < GRIDB)
                __builtin_amdgcn_s_sleep(8);
        }
        __syncthreads();
        __threadfence();                   // defensive: order acc reads after spin
        const int b = lbid - (GRIDB - BB);

        float v0 = 0.f, v1 = 0.f, v2 = 0.f, v3 = 0.f;
        if (t < 128) {
            float* ap = acc + (size_t)(4 * t) * BB + b;
            float y0 = __hip_atomic_load(ap,        __ATOMIC_RELAXED, __HIP_MEMORY_SCOPE_AGENT);
            float y1 = __hip_atomic_load(ap + BB,   __ATOMIC_RELAXED, __HIP_MEMORY_SCOPE_AGENT);
            float y2 = __hip_atomic_load(ap + 2*BB, __ATOMIC_RELAXED, __HIP_MEMORY_SCOPE_AGENT);
            float y3 = __hip_atomic_load(ap + 3*BB, __ATOMIC_RELAXED, __HIP_MEMORY_SCOPE_AGENT);
            if (!CLS) {   // re-zero for next layer
                __hip_atomic_store(ap,        0.f, __ATOMIC_RELAXED, __HIP_MEMORY_SCOPE_AGENT);
                __hip_atomic_store(ap + BB,   0.f, __ATOMIC_RELAXED, __HIP_MEMORY_SCOPE_AGENT);
                __hip_atomic_store(ap + 2*BB, 0.f, __ATOMIC_RELAXED, __HIP_MEMORY_SCOPE_AGENT);
                __hip_atomic_store(ap + 3*BB, 0.f, __ATOMIC_RELAXED, __HIP_MEMORY_SCOPE_AGENT);
            }
            v0 = silu_f(y0); v1 = silu_f(y1); v2 = silu_f(y2); v3 = silu_f(y3);
            float sum = v0 + v1 + v2 + v3;
            float ssq = v0*v0 + v1*v1 + v2*v2 + v3*v3;
#pragma unroll
            for (int off = 32; off; off >>= 1) {
                sum += __shfl_xor(sum, off);
                ssq += __shfl_xor(ssq, off);
            }
            int wid = t >> 6;
            if ((t & 63) == 0) { ls[wid] = sum; ls[2 + wid] = ssq; }
        }
        __syncthreads();
        if (!CLS) {
            if (t < 128) {
                float sum = ls[0] + ls[1], ssq = ls[2] + ls[3];
                float m   = sum * (1.0f / HH);
                float var = ssq * (1.0f / HH) - m * m;
                float rs  = rsqrtf(var + 1e-5f);
                float4 gv = ((const float4*)g)[t];
                float4 bv = ((const float4*)be)[t];
                fout4[(size_t)t * BB + b] =
                    make_float4(gv.x * (v0 - m) * rs + bv.x,
                                gv.y * (v1 - m) * rs + bv.y,
                                gv.z * (v2 - m) * rs + bv.z,
                                gv.w * (v3 - m) * rs + bv.w);
            }
        } else {
            float c0 = 0.f, c1 = 0.f;
            if (t < 128) {
                float sum = ls[0] + ls[1], ssq = ls[2] + ls[3];
                float m  = sum * (1.0f / HH);
                float var = ssq * (1.0f / HH) - m * m;
                float rs = rsqrtf(var + 1e-5f);
                float f0 = g[4*t+0] * (v0 - m) * rs + be[4*t+0];
                float f1 = g[4*t+1] * (v1 - m) * rs + be[4*t+1];
                float f2 = g[4*t+2] * (v2 - m) * rs + be[4*t+2];
                float f3 = g[4*t+3] * (v3 - m) * rs + be[4*t+3];
                float4 ca  = ((const float4*)cw)[t];
                float4 cbv = ((const float4*)cw)[HH/4 + t];
                c0 = f0*ca.x  + f1*ca.y  + f2*ca.z  + f3*ca.w;
                c1 = f0*cbv.x + f1*cbv.y + f2*cbv.z + f3*cbv.w;
#pragma unroll
                for (int off = 32; off; off >>= 1) {
                    c0 += __shfl_xor(c0, off);
                    c1 += __shfl_xor(c1, off);
                }
            }
            __syncthreads();
            if (t < 128 && (t & 63) == 0) { int wid = t >> 6; ls[wid] = c0; ls[2 + wid] = c1; }
            __syncthreads();
            if (t == 0) {
                out[b * 2 + 0] = ls[0] + ls[1] + cb[0];
                out[b * 2 + 1] = ls[2] + ls[3] + cb[1];
            }
        }
    }
}

// ---------------------------------------------------------------------------
extern "C" void kernel_launch(void* const* d_in, const int* in_sizes, int n_in,
                              void* d_out, int out_size, void* d_ws, size_t ws_size,
                              hipStream_t stream)
{
    const float* x  = (const float*)d_in[0];
    const float* t0 = (const float*)d_in[1];
    const float* s0 = (const float*)d_in[2];
    const float* w0 = (const float*)d_in[3];
    const float* g0 = (const float*)d_in[4];
    const float* b0 = (const float*)d_in[5];
    const float* t1 = (const float*)d_in[6];
    const float* s1 = (const float*)d_in[7];
    const float* w1 = (const float*)d_in[8];
    const float* g1 = (const float*)d_in[9];
    const float* b1 = (const float*)d_in[10];
    const float* t2 = (const float*)d_in[11];
    const float* s2 = (const float*)d_in[12];
    const float* w2 = (const float*)d_in[13];
    const float* g2 = (const float*)d_in[14];
    const float* b2 = (const float*)d_in[15];
    const float* cw = (const float*)d_in[16];
    const float* cb = (const float*)d_in[17];
    float* out = (float*)d_out;

    float* ws = (float*)d_ws;
    // workspace (floats): x4 524288 + acc 131072 + fA 131072 + cnt = 3.15 MB
    float4* x4  = (float4*)ws;                          // [DIN/4][BB]
    float*  acc = ws + (size_t)(DIN/4) * BB * 4;        // [HH][BB]
    float4* fA  = (float4*)(acc + (size_t)HH * BB);     // [HH/4][BB]
    int*    cnt = (int*)(acc + (size_t)HH * BB + (size_t)HH * BB);
    float4* fB  = x4;                                   // reuse x4 (dead after wav0)

    tz_k<<<512, 256, 0, stream>>>(x, x4, acc, cnt);

    // ---- layer 0: DIN -> HH (+fused SiLU/LN) ----
    wavf_k<DIN, 0><<<dim3(HH/4, NSL), 256, 0, stream>>>(
        x4, s0, t0, w0, acc, cnt + 0, g0, b0, fA, cw, cb, out);

    // ---- layer 1: HH -> HH (+fused SiLU/LN) ----
    wavf_k<HH, 0><<<dim3(HH/4, NSL), 256, 0, stream>>>(
        (const float4*)fA, s1, t1, w1, acc, cnt + 1, g1, b1, fB, cw, cb, out);

    // ---- layer 2: HH -> HH (+fused SiLU/LN + classifier) ----
    wavf_k<HH, 1><<<dim3(HH/4, NSL), 256, 0, stream>>>(
        (const float4*)fB, s2, t2, w2, acc, cnt + 2, g2, b2, fA, cw, cb, out);
}

// Round 13
// 566.468 us; speedup vs baseline: 1.1890x; 1.1890x over previous
//
#include <hip/hip_runtime.h>
#include <math.h>

#define BB    256
#define DIN   2048
#define HH    512
#define NSL   16
#define NQ    (HH/4)

#define NEG_HALF_LOG2E (-0.72134752044448170368f)
#define LOG2E           1.44269504088896340736f
#define LN2             0.69314718055994530942f

typedef float v2f __attribute__((ext_vector_type(2)));

__device__ __forceinline__ float fexp2(float x) { return __builtin_amdgcn_exp2f(x); }
__device__ __forceinline__ float silu_f(float y)
{
    return y * __builtin_amdgcn_rcpf(1.f + fexp2(-y * LOG2E));
}

// ---------------------------------------------------------------------------
// tz: transpose x [BB][DIN] -> x4 [DIN/4][BB]; zero acc, stats, qcnt.
// ---------------------------------------------------------------------------
__global__ __launch_bounds__(256) void tz_k(
    const float* __restrict__ in, float4* __restrict__ out4,
    float* __restrict__ acc, float* __restrict__ stats, int* __restrict__ qcnt)
{
    __shared__ float tile[32][33];
    int bid = blockIdx.x, t = threadIdx.x;
    acc[bid * 256 + t] = 0.0f;                 // 512*256 == HH*BB
    int j = bid * 256 + t;
    if (j < 3 * 2 * BB) stats[j] = 0.0f;       // 3 layers x 512
    if (j < 3 * NQ)     qcnt[j]  = 0;          // 3 layers x 128
    int ct = bid & 63, rt = bid >> 6;
    int c0 = ct * 32, r0 = rt * 32;
    int tx = t & 31, ty = t >> 5;
#pragma unroll
    for (int k = 0; k < 4; k++)
        tile[ty + 8*k][tx] = in[(size_t)(r0 + ty + 8*k) * DIN + c0 + tx];
    __syncthreads();
    float4 v = make_float4(tile[tx][4*ty + 0], tile[tx][4*ty + 1],
                           tile[tx][4*ty + 2], tile[tx][4*ty + 3]);
    out4[(size_t)(c0/4 + ty) * BB + (r0 + tx)] = v;
}

// ---------------------------------------------------------------------------
// wavelet + last-arriver finisher (no spinning).
// ---------------------------------------------------------------------------
#define WAV_RR(PB, OFF, XSC) {                                    \
    float4 R = *(const float4*)((PB) + (OFF));                    \
    float4 T = *(const float4*)((PB) + (OFF) + 4);                \
    float4 W = *(const float4*)((PB) + (OFF) + 8);                \
    v2f xx  = {(XSC), (XSC)};                                     \
    v2f R01 = {R.x, R.y}, R23 = {R.z, R.w};                       \
    v2f T01 = {T.x, T.y}, T23 = {T.z, T.w};                       \
    v2f W01 = {W.x, W.y}, W23 = {W.z, W.w};                       \
    v2f d01 = __builtin_elementwise_fma(xx, R01, -T01);           \
    v2f d23 = __builtin_elementwise_fma(xx, R23, -T23);           \
    v2f u01 = d01 * d01,  u23 = d23 * d23;                        \
    v2f g01 = u01 * k2,   g23 = u23 * k2;                         \
    v2f e01, e23;                                                 \
    e01.x = fexp2(g01.x); e01.y = fexp2(g01.y);                   \
    e23.x = fexp2(g23.x); e23.y = fexp2(g23.y);                   \
    v2f p01 = __builtin_elementwise_fma(-W01, u01, W01);          \
    v2f p23 = __builtin_elementwise_fma(-W23, u23, W23);          \
    a01 = __builtin_elementwise_fma(p01, e01, a01);               \
    a23 = __builtin_elementwise_fma(p23, e23, a23); }

template<int D, int AFF>
__global__ __launch_bounds__(256, 8) void wavf_k(
    const float4* __restrict__ fin4,
    const float*  __restrict__ ss,
    const float*  __restrict__ tt,
    const float*  __restrict__ ww,
    float* __restrict__ acc, int* __restrict__ qcnt,
    const float* __restrict__ stats_in,
    const float* __restrict__ g_in, const float* __restrict__ be_in,
    float4* __restrict__ fout4, float* __restrict__ stats_out)
{
    constexpr int G     = (D / 4) / NSL;   // 32 (L0) or 8 (L1/2)
    constexpr int SLICE = G * 4;           // 128 or 32
    constexpr int LSH   = (SLICE == 128) ? 7 : 5;

    __shared__ float P[G * 48];
    __shared__ int fin_flag;

    const int q  = blockIdx.x;
    const int sl = blockIdx.y;
    const int t  = threadIdx.x;

    for (int e = t; e < 4 * SLICE; e += 256) {
        int oo = e >> LSH;
        int ii = e & (SLICE - 1);
        size_t idx = (size_t)(q * 4 + oo) * D + (size_t)sl * SLICE + ii;
        float v  = ss[idx];
        float e2 = fexp2(-fabsf(v) * LOG2E);
        float sp = fmaxf(v, 0.0f) + LN2 * __builtin_amdgcn_logf(1.0f + e2);
        float rv = __builtin_amdgcn_rcpf(0.001f + sp + 1e-8f);
        int gg = ii >> 2, rr = ii & 3;
        P[gg * 48 + rr * 12 + 0 + oo] = rv;
        P[gg * 48 + rr * 12 + 4 + oo] = tt[idx] * rv;
        P[gg * 48 + rr * 12 + 8 + oo] = ww[idx];
    }

    float m_b = 0.f, rs_b = 0.f;
    if (AFF) {
        float sum = stats_in[2 * t], ssq = stats_in[2 * t + 1];
        m_b  = sum * (1.0f / HH);
        float var = ssq * (1.0f / HH) - m_b * m_b;
        rs_b = rsqrtf(var + 1e-5f);
    }
    __syncthreads();

    const float4* xp = fin4 + (size_t)sl * G * BB + t;
    v2f a01 = {0.f, 0.f}, a23 = {0.f, 0.f};
    const v2f k2 = {NEG_HALF_LOG2E, NEG_HALF_LOG2E};

#pragma unroll 2
    for (int gi = 0; gi < G; ++gi) {
        const float* pb = &P[gi * 48];
        float4 xv = xp[(size_t)gi * BB];
        if (AFF) {
            int i0 = sl * SLICE + gi * 4;
            float4 g4 = *(const float4*)(g_in  + i0);
            float4 b4 = *(const float4*)(be_in + i0);
            float a0_ = g4.x * rs_b, a1_ = g4.y * rs_b;
            float a2_ = g4.z * rs_b, a3_ = g4.w * rs_b;
            xv.x = fmaf(xv.x, a0_, fmaf(-m_b, a0_, b4.x));
            xv.y = fmaf(xv.y, a1_, fmaf(-m_b, a1_, b4.y));
            xv.z = fmaf(xv.z, a2_, fmaf(-m_b, a2_, b4.z));
            xv.w = fmaf(xv.w, a3_, fmaf(-m_b, a3_, b4.w));
        }
        WAV_RR(pb,  0, xv.x)
        WAV_RR(pb, 12, xv.y)
        WAV_RR(pb, 24, xv.z)
        WAV_RR(pb, 36, xv.w)
    }

    float* dst = acc + (size_t)(4 * q) * BB + t;
    unsafeAtomicAdd(dst,        a01.x);
    unsafeAtomicAdd(dst + BB,   a01.y);
    unsafeAtomicAdd(dst + 2*BB, a23.x);
    unsafeAtomicAdd(dst + 3*BB, a23.y);

    __threadfence();
    __syncthreads();
    if (t == 0) {
        int old = atomicAdd(&qcnt[q], 1);
        fin_flag = (old == NSL - 1);
    }
    __syncthreads();
    if (fin_flag) {
        __threadfence();
        float* ap = acc + (size_t)(4 * q) * BB + t;   // b = t
        float y0 = __hip_atomic_load(ap,        __ATOMIC_RELAXED, __HIP_MEMORY_SCOPE_AGENT);
        float y1 = __hip_atomic_load(ap + BB,   __ATOMIC_RELAXED, __HIP_MEMORY_SCOPE_AGENT);
        float y2 = __hip_atomic_load(ap + 2*BB, __ATOMIC_RELAXED, __HIP_MEMORY_SCOPE_AGENT);
        float y3 = __hip_atomic_load(ap + 3*BB, __ATOMIC_RELAXED, __HIP_MEMORY_SCOPE_AGENT);
        __hip_atomic_store(ap,        0.f, __ATOMIC_RELAXED, __HIP_MEMORY_SCOPE_AGENT);
        __hip_atomic_store(ap + BB,   0.f, __ATOMIC_RELAXED, __HIP_MEMORY_SCOPE_AGENT);
        __hip_atomic_store(ap + 2*BB, 0.f, __ATOMIC_RELAXED, __HIP_MEMORY_SCOPE_AGENT);
        __hip_atomic_store(ap + 3*BB, 0.f, __ATOMIC_RELAXED, __HIP_MEMORY_SCOPE_AGENT);

        float v0 = silu_f(y0), v1 = silu_f(y1), v2 = silu_f(y2), v3 = silu_f(y3);
        fout4[(size_t)q * BB + t] = make_float4(v0, v1, v2, v3);   // raw silu
        float sum = v0 + v1 + v2 + v3;
        float ssq = v0*v0 + v1*v1 + v2*v2 + v3*v3;
        unsafeAtomicAdd(&stats_out[2 * t],     sum);
        unsafeAtomicAdd(&stats_out[2 * t + 1], ssq);
    }
}

// ---------------------------------------------------------------------------
// classifier: block = batch b; normalize f2raw with stats2 + (g2,b2), dot cw.
// ---------------------------------------------------------------------------
__global__ __launch_bounds__(256) void cls_k(
    const float4* __restrict__ f4, const float* __restrict__ stats,
    const float* __restrict__ g, const float* __restrict__ be,
    const float* __restrict__ cw, const float* __restrict__ cb,
    float* __restrict__ out)
{
    __shared__ float ls[4];
    const int b = blockIdx.x, t = threadIdx.x;
    float sum = stats[2 * b], ssq = stats[2 * b + 1];
    float m  = sum * (1.0f / HH);
    float var = ssq * (1.0f / HH) - m * m;
    float rs = rsqrtf(var + 1e-5f);
    float c0 = 0.f, c1 = 0.f;
    if (t < 128) {
        float4 v = f4[(size_t)t * BB + b];
        float f0 = g[4*t+0] * (v.x - m) * rs + be[4*t+0];
        float f1 = g[4*t+1] * (v.y - m) * rs + be[4*t+1];
        float f2 = g[4*t+2] * (v.z - m) * rs + be[4*t+2];
        float f3 = g[4*t+3] * (v.w - m) * rs + be[4*t+3];
        float4 ca  = ((const float4*)cw)[t];
        float4 cbv = ((const float4*)cw)[HH/4 + t];
        c0 = f0*ca.x  + f1*ca.y  + f2*ca.z  + f3*ca.w;
        c1 = f0*cbv.x + f1*cbv.y + f2*cbv.z + f3*cbv.w;
#pragma unroll
        for (int off = 32; off; off >>= 1) {
            c0 += __shfl_xor(c0, off);
            c1 += __shfl_xor(c1, off);
        }
    }
    if (t < 128 && (t & 63) == 0) { int wid = t >> 6; ls[wid] = c0; ls[2 + wid] = c1; }
    __syncthreads();
    if (t == 0) {
        out[b * 2 + 0] = ls[0] + ls[1] + cb[0];
        out[b * 2 + 1] = ls[2] + ls[3] + cb[1];
    }
}

// ---------------------------------------------------------------------------
extern "C" void kernel_launch(void* const* d_in, const int* in_sizes, int n_in,
                              void* d_out, int out_size, void* d_ws, size_t ws_size,
                              hipStream_t stream)
{
    const float* x  = (const float*)d_in[0];
    const float* t0 = (const float*)d_in[1];
    const float* s0 = (const float*)d_in[2];
    const float* w0 = (const float*)d_in[3];
    const float* g0 = (const float*)d_in[4];
    const float* b0 = (const float*)d_in[5];
    const float* t1 = (const float*)d_in[6];
    const float* s1 = (const float*)d_in[7];
    const float* w1 = (const float*)d_in[8];
    const float* g1 = (const float*)d_in[9];
    const float* b1 = (const float*)d_in[10];
    const float* t2 = (const float*)d_in[11];
    const float* s2 = (const float*)d_in[12];
    const float* w2 = (const float*)d_in[13];
    const float* g2 = (const float*)d_in[14];
    const float* b2 = (const float*)d_in[15];
    const float* cw = (const float*)d_in[16];
    const float* cb = (const float*)d_in[17];
    float* out = (float*)d_out;

    float* ws = (float*)d_ws;
    // floats: x4 524288 | acc 131072 | f0 131072 | f2 131072 | stats 1536 | qcnt 384i
    float4* x4    = (float4*)ws;
    float*  acc   = ws + (size_t)(DIN/4) * BB * 4;
    float4* f0    = (float4*)(acc + (size_t)HH * BB);
    float4* f2    = f0 + (size_t)NQ * BB;
    float*  stats = (float*)(f2 + (size_t)NQ * BB);
    int*    qcnt  = (int*)(stats + 3 * 2 * BB);
    float4* f1    = x4;   // reuse x4 (dead after wav0)

    tz_k<<<512, 256, 0, stream>>>(x, x4, acc, stats, qcnt);

    // layer 0: raw x4 -> f0 (raw silu) + stats[0]
    wavf_k<DIN, 0><<<dim3(NQ, NSL), 256, 0, stream>>>(
        x4, s0, t0, w0, acc, qcnt, nullptr, nullptr, nullptr, f0, stats);

    // layer 1: f0 affine(stats0,g0,b0) -> f1 + stats[1]
    wavf_k<HH, 1><<<dim3(NQ, NSL), 256, 0, stream>>>(
        f0, s1, t1, w1, acc, qcnt + NQ, stats, g0, b0, f1, stats + 2*BB);

    // layer 2: f1 affine(stats1,g1,b1) -> f2 + stats[2]
    wavf_k<HH, 1><<<dim3(NQ, NSL), 256, 0, stream>>>(
        f1, s2, t2, w2, acc, qcnt + 2*NQ, stats + 2*BB, g1, b1, f2, stats + 4*BB);

    // classifier: f2 affine(stats2,g2,b2) . cw + cb
    cls_k<<<BB, 256, 0, stream>>>(f2, stats + 4*BB, g2, b2, cw, cb, out);
}